// Round 1
// baseline (94.085 us; speedup 1.0000x reference)
//
#include <hip/hip_runtime.h>

// Problem constants (fixed by the reference file).
#define L_LABELS 16
#define S_PER    8
#define D_FEAT   1024
#define ROWS_PER_LABEL (3 * S_PER)   // 3 feature sets x 8 samples = 24 rows per label

// Kernel 1: one block per (q-row-in-label-j, label i, label j), i < j.
// Block = 256 threads; each thread owns 4 consecutive floats (float4) of the
// 1024-dim rows. Computes max over the 24 p-rows of |1 - meanL1(p, q)| and
// atomicMax's it into ws_max[i*16+j] (uint bit-pattern, values >= 0).
__global__ __launch_bounds__(256) void idml_pairmax_kernel(
    const float* __restrict__ f1,
    const float* __restrict__ f2,
    const float* __restrict__ f3,
    unsigned int* __restrict__ ws_max)
{
    const int qIdx = blockIdx.x;            // 0..23: which row of label j
    const int i = blockIdx.y;               // label i
    const int j = blockIdx.z;               // label j
    if (i >= j) return;                     // only upper triangle needed

    const float* feats[3] = {f1, f2, f3};
    const int tid  = threadIdx.x;
    const int wave = tid >> 6;
    const int lane = tid & 63;

    const int qSet  = qIdx >> 3;            // 0..2
    const int qSamp = qIdx & 7;             // 0..7
    const float* qrow = feats[qSet] + (size_t)(j * S_PER + qSamp) * D_FEAT;
    const float4 qv = *reinterpret_cast<const float4*>(qrow + tid * 4);

    __shared__ float partials[ROWS_PER_LABEL][4];

    #pragma unroll 4
    for (int p = 0; p < ROWS_PER_LABEL; ++p) {
        const int pSet  = p >> 3;
        const int pSamp = p & 7;
        const float* prow = feats[pSet] + (size_t)(i * S_PER + pSamp) * D_FEAT;
        const float4 pv = *reinterpret_cast<const float4*>(prow + tid * 4);
        float s = fabsf(pv.x - qv.x) + fabsf(pv.y - qv.y)
                + fabsf(pv.z - qv.z) + fabsf(pv.w - qv.w);
        // wave-64 tree reduce
        #pragma unroll
        for (int off = 32; off > 0; off >>= 1)
            s += __shfl_down(s, off, 64);
        if (lane == 0) partials[p][wave] = s;
    }
    __syncthreads();

    if (tid == 0) {
        float vmax = 0.0f;
        #pragma unroll
        for (int p = 0; p < ROWS_PER_LABEL; ++p) {
            const float tot = partials[p][0] + partials[p][1]
                            + partials[p][2] + partials[p][3];
            const float d = tot * (1.0f / (float)D_FEAT);
            const float v = fabsf(1.0f - d);
            vmax = fmaxf(vmax, v);
        }
        // v >= 0, so uint bit-pattern ordering == float ordering
        atomicMax(&ws_max[i * L_LABELS + j], __float_as_uint(vmax));
    }
}

// Kernel 2: one wave reduces the 120 upper-triangle maxima to their mean.
__global__ __launch_bounds__(64) void idml_finalize_kernel(
    const unsigned int* __restrict__ ws_max,
    float* __restrict__ out)
{
    const int lane = threadIdx.x;
    float s = 0.0f;
    for (int idx = lane; idx < L_LABELS * L_LABELS; idx += 64) {
        const int i = idx >> 4;
        const int j = idx & 15;
        if (i < j) s += __uint_as_float(ws_max[idx]);
    }
    #pragma unroll
    for (int off = 32; off > 0; off >>= 1)
        s += __shfl_down(s, off, 64);
    if (lane == 0) out[0] = s * (1.0f / 120.0f);
}

extern "C" void kernel_launch(void* const* d_in, const int* in_sizes, int n_in,
                              void* d_out, int out_size, void* d_ws, size_t ws_size,
                              hipStream_t stream) {
    const float* f1 = (const float*)d_in[0];
    const float* f2 = (const float*)d_in[1];
    const float* f3 = (const float*)d_in[2];
    // d_in[3] = labels (int32) — layout is fixed (contiguous groups of 8), unused.
    float* out = (float*)d_out;
    unsigned int* ws_max = (unsigned int*)d_ws;   // 256 slots, only i<j used

    // ws is re-poisoned to 0xAA before every launch — zero it (0u == 0.0f).
    hipMemsetAsync(ws_max, 0, L_LABELS * L_LABELS * sizeof(unsigned int), stream);

    dim3 grid(ROWS_PER_LABEL, L_LABELS, L_LABELS);
    idml_pairmax_kernel<<<grid, 256, 0, stream>>>(f1, f2, f3, ws_max);
    idml_finalize_kernel<<<1, 64, 0, stream>>>(ws_max, out);
}

// Round 2
// 79.060 us; speedup vs baseline: 1.1901x; 1.1901x over previous
//
#include <hip/hip_runtime.h>

// Problem constants (fixed by the reference file).
#define L_LABELS 16
#define S_PER    8
#define D_FEAT   1024
#define NPAIRS   120                 // 16*15/2 label pairs, i < j
#define ROWS_PER_LABEL 24            // 3 feature sets x 8 samples

// Main kernel: grid (120, 9), block 256 (4 waves).
// Each wave owns a 4x4 tile of (q-row, p-row) pairs for one (i,j) label pair:
//   36 tiles (6x6 groups of 4 rows) x 4 waves/block x 9 blocks.y = 24x24 pairs.
// Register-tiled: per 256-float chunk a lane loads 4 q-float4 + 4 p-float4 and
// accumulates 16 pair partial L1 sums (6 VALU ops per load). One 6-step
// shfl_xor butterfly per tile reduces all 16 accumulators across the wave.
__global__ __launch_bounds__(256) void idml_main_kernel(
    const float* __restrict__ f1,
    const float* __restrict__ f2,
    const float* __restrict__ f3,
    unsigned int* __restrict__ ws_max)
{
    // Decode blockIdx.x -> (i, j), i < j (uniform scalar loop, <=15 iters).
    int rem = blockIdx.x, i = 0;
    while (rem >= L_LABELS - 1 - i) { rem -= L_LABELS - 1 - i; ++i; }
    const int j = i + 1 + rem;

    const int wave = threadIdx.x >> 6;
    const int lane = threadIdx.x & 63;
    const int t  = blockIdx.y * 4 + wave;   // tile id 0..35
    const int qt = t / 6;                   // q 4-row group (label j)
    const int pt = t % 6;                   // p 4-row group (label i)

    const float* feats[3] = {f1, f2, f3};
    const float* qp[4];
    const float* pp[4];
    #pragma unroll
    for (int k = 0; k < 4; ++k) {
        const int qr = qt * 4 + k;          // row 0..23 within label j
        const int pr = pt * 4 + k;          // row 0..23 within label i
        qp[k] = feats[qr >> 3] + ((size_t)(j * S_PER + (qr & 7)) << 10);
        pp[k] = feats[pr >> 3] + ((size_t)(i * S_PER + (pr & 7)) << 10);
    }

    float acc[4][4] = {};
    #pragma unroll
    for (int c = 0; c < 4; ++c) {           // 4 chunks of 256 floats
        float4 qv[4], pv[4];
        #pragma unroll
        for (int k = 0; k < 4; ++k) {
            qv[k] = reinterpret_cast<const float4*>(qp[k] + c * 256)[lane];
            pv[k] = reinterpret_cast<const float4*>(pp[k] + c * 256)[lane];
        }
        #pragma unroll
        for (int a = 0; a < 4; ++a)
            #pragma unroll
            for (int b = 0; b < 4; ++b)
                acc[a][b] += fabsf(qv[a].x - pv[b].x) + fabsf(qv[a].y - pv[b].y)
                           + fabsf(qv[a].z - pv[b].z) + fabsf(qv[a].w - pv[b].w);
    }

    // Butterfly reduce all 16 accumulators across the 64 lanes.
    #pragma unroll
    for (int off = 32; off >= 1; off >>= 1) {
        #pragma unroll
        for (int a = 0; a < 4; ++a)
            #pragma unroll
            for (int b = 0; b < 4; ++b)
                acc[a][b] += __shfl_xor(acc[a][b], off, 64);
    }

    float vmax = 0.0f;
    #pragma unroll
    for (int a = 0; a < 4; ++a)
        #pragma unroll
        for (int b = 0; b < 4; ++b)
            vmax = fmaxf(vmax, fabsf(1.0f - acc[a][b] * (1.0f / (float)D_FEAT)));

    // vmax >= 0, so uint bit-pattern ordering == float ordering.
    if (lane == 0)
        atomicMax(&ws_max[i * L_LABELS + j], __float_as_uint(vmax));
}

// Finalize: one wave reduces the 120 upper-triangle maxima to their mean.
__global__ __launch_bounds__(64) void idml_finalize_kernel(
    const unsigned int* __restrict__ ws_max,
    float* __restrict__ out)
{
    const int lane = threadIdx.x;
    float s = 0.0f;
    for (int idx = lane; idx < L_LABELS * L_LABELS; idx += 64) {
        const int a = idx >> 4;
        const int b = idx & 15;
        if (a < b) s += __uint_as_float(ws_max[idx]);
    }
    #pragma unroll
    for (int off = 32; off > 0; off >>= 1)
        s += __shfl_down(s, off, 64);
    if (lane == 0) out[0] = s * (1.0f / (float)NPAIRS);
}

extern "C" void kernel_launch(void* const* d_in, const int* in_sizes, int n_in,
                              void* d_out, int out_size, void* d_ws, size_t ws_size,
                              hipStream_t stream) {
    const float* f1 = (const float*)d_in[0];
    const float* f2 = (const float*)d_in[1];
    const float* f3 = (const float*)d_in[2];
    // d_in[3] = labels (int32) — layout fixed (contiguous groups of 8), unused.
    float* out = (float*)d_out;
    unsigned int* ws_max = (unsigned int*)d_ws;   // 256 slots, only i<j used

    // ws is re-poisoned to 0xAA before every launch — zero it (0u == 0.0f).
    hipMemsetAsync(ws_max, 0, L_LABELS * L_LABELS * sizeof(unsigned int), stream);

    dim3 grid(NPAIRS, 9);
    idml_main_kernel<<<grid, 256, 0, stream>>>(f1, f2, f3, ws_max);
    idml_finalize_kernel<<<1, 64, 0, stream>>>(ws_max, out);
}

// Round 3
// 69.814 us; speedup vs baseline: 1.3476x; 1.1324x over previous
//
#include <hip/hip_runtime.h>

// Problem constants (fixed by the reference file).
#define L_LABELS 16
#define S_PER    8
#define D_FEAT   1024
#define NPAIRS   120                 // 16*15/2 label pairs, i < j
#define SUBY     9                   // 36 tiles / 4 waves per block

// Kernel A: grid (120, 9), block 256 (4 waves).
// Each wave owns a 4x4 tile of (q-row, p-row) pairs for one (i,j) label pair.
// Register-tiled: per 256-float chunk a lane loads 4 q-float4 + 4 p-float4 and
// accumulates 16 pair partial L1 sums. One 6-step shfl_xor butterfly per tile
// reduces the 16 accumulators across the wave; block max via LDS; plain store
// (no atomics, no zero-init needed — every slot written every launch).
__global__ __launch_bounds__(256) void idml_main_kernel(
    const float* __restrict__ f1,
    const float* __restrict__ f2,
    const float* __restrict__ f3,
    float* __restrict__ ws_part)
{
    // Decode blockIdx.x -> (i, j), i < j (uniform scalar loop, <=15 iters).
    int rem = blockIdx.x, i = 0;
    while (rem >= L_LABELS - 1 - i) { rem -= L_LABELS - 1 - i; ++i; }
    const int j = i + 1 + rem;

    const int wave = threadIdx.x >> 6;
    const int lane = threadIdx.x & 63;
    const int t  = blockIdx.y * 4 + wave;   // tile id 0..35
    const int qt = t / 6;                   // q 4-row group (label j)
    const int pt = t % 6;                   // p 4-row group (label i)

    const float* feats[3] = {f1, f2, f3};
    const float* qp[4];
    const float* pp[4];
    #pragma unroll
    for (int k = 0; k < 4; ++k) {
        const int qr = qt * 4 + k;          // row 0..23 within label j
        const int pr = pt * 4 + k;          // row 0..23 within label i
        qp[k] = feats[qr >> 3] + ((size_t)(j * S_PER + (qr & 7)) << 10);
        pp[k] = feats[pr >> 3] + ((size_t)(i * S_PER + (pr & 7)) << 10);
    }

    float acc[4][4] = {};
    #pragma unroll
    for (int c = 0; c < 4; ++c) {           // 4 chunks of 256 floats
        float4 qv[4], pv[4];
        #pragma unroll
        for (int k = 0; k < 4; ++k) {
            qv[k] = reinterpret_cast<const float4*>(qp[k] + c * 256)[lane];
            pv[k] = reinterpret_cast<const float4*>(pp[k] + c * 256)[lane];
        }
        #pragma unroll
        for (int a = 0; a < 4; ++a)
            #pragma unroll
            for (int b = 0; b < 4; ++b)
                acc[a][b] += fabsf(qv[a].x - pv[b].x) + fabsf(qv[a].y - pv[b].y)
                           + fabsf(qv[a].z - pv[b].z) + fabsf(qv[a].w - pv[b].w);
    }

    // Butterfly reduce all 16 accumulators across the 64 lanes.
    #pragma unroll
    for (int off = 32; off >= 1; off >>= 1) {
        #pragma unroll
        for (int a = 0; a < 4; ++a)
            #pragma unroll
            for (int b = 0; b < 4; ++b)
                acc[a][b] += __shfl_xor(acc[a][b], off, 64);
    }

    float vmax = 0.0f;
    #pragma unroll
    for (int a = 0; a < 4; ++a)
        #pragma unroll
        for (int b = 0; b < 4; ++b)
            vmax = fmaxf(vmax, fabsf(1.0f - acc[a][b] * (1.0f / (float)D_FEAT)));

    // Block max across the 4 waves, then one plain store per block.
    __shared__ float wmax[4];
    if (lane == 0) wmax[wave] = vmax;
    __syncthreads();
    if (threadIdx.x == 0) {
        const float m = fmaxf(fmaxf(wmax[0], wmax[1]), fmaxf(wmax[2], wmax[3]));
        ws_part[blockIdx.x * SUBY + blockIdx.y] = m;
    }
}

// Kernel B: 1 block, 128 threads. Max over each pair's 9 sub-results, then
// mean over the 120 pairs.
__global__ __launch_bounds__(128) void idml_finalize_kernel(
    const float* __restrict__ ws_part,
    float* __restrict__ out)
{
    const int t = threadIdx.x;
    float s = 0.0f;
    if (t < NPAIRS) {
        const float* p = ws_part + t * SUBY;
        float m = p[0];
        #pragma unroll
        for (int k = 1; k < SUBY; ++k) m = fmaxf(m, p[k]);
        s = m;
    }
    #pragma unroll
    for (int off = 32; off >= 1; off >>= 1)
        s += __shfl_xor(s, off, 64);
    __shared__ float partial[2];
    if ((t & 63) == 0) partial[t >> 6] = s;
    __syncthreads();
    if (t == 0) out[0] = (partial[0] + partial[1]) * (1.0f / (float)NPAIRS);
}

extern "C" void kernel_launch(void* const* d_in, const int* in_sizes, int n_in,
                              void* d_out, int out_size, void* d_ws, size_t ws_size,
                              hipStream_t stream) {
    const float* f1 = (const float*)d_in[0];
    const float* f2 = (const float*)d_in[1];
    const float* f3 = (const float*)d_in[2];
    // d_in[3] = labels (int32) — layout fixed (contiguous groups of 8), unused.
    float* out = (float*)d_out;
    float* ws_part = (float*)d_ws;   // 120*9 floats, every slot written each launch

    dim3 grid(NPAIRS, SUBY);
    idml_main_kernel<<<grid, 256, 0, stream>>>(f1, f2, f3, ws_part);
    idml_finalize_kernel<<<1, 128, 0, stream>>>(ws_part, out);
}